// Round 20
// baseline (148.182 us; speedup 1.0000x reference)
//
#include <hip/hip_runtime.h>

// IGANN: per-feature 2-layer MLPs (1->16->16->1), summed over 256 features + linear term.
// R20 = R19 (best: 107.8; interleaved W1|b1 ds_read2_b64 + (b2,w3) float2) + issue diet #2:
//     (a) fi-loop FULLY unrolled (plain pragma, no launch_bounds): rolled loop forced
//         per-iteration lgkmcnt waits on xv ds_reads; unroll lets the scheduler pipeline
//         LDS->MFMA across u-iters. VGPR may rise ~70->90 — fine, spills only ever came
//         from min-waves pressure (R3/R4/R8), never from plain bounds.
//     (b) epilogue deleted: lin computed in-loop from the already-loaded xv f16 values
//         (16 cvt+fma in-loop replace 16 ds_read_u16 + 16 cvt + 16 fma per thread);
//         g==0 lanes deliver lin + b3s + bb via the second atomic stream (R17-proven).
//     Evidence: structure flat (R9/R10/R14/R17/R18 ~32-37 us); only issue-count moves it
//     (R19: -32 ds_read -> -1.3 us, as predicted).

typedef float    f32x4 __attribute__((ext_vector_type(4)));
typedef _Float16 f16x4 __attribute__((ext_vector_type(4)));
typedef __fp16   pk16x2 __attribute__((ext_vector_type(2)));

__device__ __forceinline__ f16x4 cvt4(f32x4 v) {
    pk16x2 lo = __builtin_amdgcn_cvt_pkrtz(v[0], v[1]);
    pk16x2 hi = __builtin_amdgcn_cvt_pkrtz(v[2], v[3]);
    union { unsigned u[2]; f16x4 h; } un;
    un.u[0] = __builtin_bit_cast(unsigned, lo);
    un.u[1] = __builtin_bit_cast(unsigned, hi);
    return un.h;
}

__device__ __forceinline__ f16x4 relu_h(f16x4 v) {
    f16x4 z = {};
    return __builtin_elementwise_max(v, z);
}

__device__ __forceinline__ f32x4 relu_f(f32x4 v) {
    f32x4 z = {0.f, 0.f, 0.f, 0.f};
    return __builtin_elementwise_max(v, z);
}

#define FCHUNK 16   // features per block (16 groups of 16 = 256)
#define XR     20   // x LDS row stride in f16 (40 B, 8-B aligned, conflict-free — R9-proven)

__global__ __launch_bounds__(256) void igann_kernel(
    const float* __restrict__ x,  const float* __restrict__ la,
    const float* __restrict__ bb, const float* __restrict__ W1,
    const float* __restrict__ b1, const float* __restrict__ W2,
    const float* __restrict__ b2, const float* __restrict__ W3,
    const float* __restrict__ b3, float* __restrict__ out)
{
    const int tid = threadIdx.x;
    const int l   = tid & 63;     // lane
    const int w   = tid >> 6;     // wave in block (0..3)
    const int r   = l & 15;       // MFMA row m (A) / col n (D)
    const int g   = l >> 4;       // k-group
    const int g4  = g * 4;

    const int rb = blockIdx.x >> 4;    // row block (0..127), 256 rows each
    const int fg = blockIdx.x & 15;    // feature group (0..15)
    const int f0 = fg * FCHUNK;
    const int rowbase = rb * 256;

    __shared__ _Float16 xs [256 * XR];           // 10240 B: x slice [row][col16+pad]
    __shared__ _Float16 w2s[FCHUNK * 16 * 16];   //  8192 B: [f][n][k16] dense
    __shared__ _Float16 wbs[FCHUNK * 4 * 8];     //  1024 B: [f][g][w1 x4 | b1 x4]
    __shared__ float2   bws[FCHUNK * 16];        //  2048 B: [f][n] -> (b2, w3)
                                                 //  -> 21504 B total

    // ---- stage x slice (coalesced: 4 lanes cover one 64-B row-slice) ----
    {
        const int rr = tid >> 2;          // 0..63
        const int c4 = (tid & 3) * 4;     // 0,4,8,12
        #pragma unroll
        for (int it = 0; it < 4; ++it) {
            const int row = it * 64 + rr;
            f32x4 v = *(const f32x4*)(x + (size_t)(rowbase + row) * 256 + f0 + c4);
            *(f16x4*)(xs + row * XR + c4) = cvt4(v);
        }
    }
    // ---- stage W2 (thread tid owns (f,n)=(tid>>4, tid&15)) ----
    {
        const int f = tid >> 4, n = tid & 15;
        const float* src = W2 + ((size_t)(f0 + f) * 16 + n) * 16;
        _Float16* dst = w2s + (f * 16 + n) * 16;
        #pragma unroll
        for (int q = 0; q < 4; ++q) {
            f32x4 v = *(const f32x4*)(src + q * 4);
            *(f16x4*)(dst + q * 4) = cvt4(v);
        }
    }
    // ---- stage interleaved W1|b1 (scalar f16 stores; thread tid owns (f,k)) ----
    {
        const int f = tid >> 4, k = tid & 15;
        const int base = f * 32 + (k >> 2) * 8 + (k & 3);   // [f][g][lo4|hi4]
        wbs[base]     = (_Float16)W1[(size_t)(f0 + f) * 16 + k];
        wbs[base + 4] = (_Float16)b1[(size_t)(f0 + f) * 16 + k];
    }
    // ---- stage (b2, w3) float2 pairs ----
    {
        const int f = tid >> 4, n = tid & 15;
        bws[tid] = make_float2(b2[(size_t)(f0 + f) * 16 + n],
                               W3[(size_t)(f0 + f) * 16 + n]);
    }
    __syncthreads();

    const _Float16* xw = xs + (w * 64 + r) * XR;

    f32x4 acc[4];     // [tile][j]: D row g4+j (batch row within tile), col r (channel)
    float lin[4];     // linear term for row t*16+r (duplicated across g; g==0 delivers)
    #pragma unroll
    for (int t = 0; t < 4; ++t) { acc[t] = (f32x4){0.f, 0.f, 0.f, 0.f}; lin[t] = 0.f; }

    #pragma unroll
    for (int fi = 0; fi < FCHUNK; fi += 4) {   // FULL unroll: scheduler pipelines ds->MFMA
        f16x4 xv[4];
        #pragma unroll
        for (int t = 0; t < 4; ++t)
            xv[t] = *(const f16x4*)(xw + t * 16 * XR + fi);

        // linear term from the staged f16 values (la wave-uniform -> s_loads)
        #pragma unroll
        for (int t = 0; t < 4; ++t)
            #pragma unroll
            for (int c = 0; c < 4; ++c)
                lin[t] = fmaf((float)xv[t][c], la[f0 + fi + c], lin[t]);

        #pragma unroll
        for (int u = 0; u < 4; ++u) {
            const int f = fi + u;
            // adjacent f16x4 reads (8 B apart) -> ds_read2_b64
            f16x4 w1h   = *(const f16x4*)(wbs + f * 32 + g * 8);
            f16x4 b1h   = *(const f16x4*)(wbs + f * 32 + g * 8 + 4);
            f16x4 bfrag = *(const f16x4*)(w2s + (f * 16 + r) * 16 + g4);
            const float2 bw = bws[f * 16 + r];          // one ds_read_b64
            const f32x4 cinit = {bw.x, bw.x, bw.x, bw.x};   // b2 folded into MFMA C
            const f32x4 w3k4  = {bw.y, bw.y, bw.y, bw.y};

            #pragma unroll
            for (int t = 0; t < 4; ++t) {
                const _Float16 s = xv[t][u];
                f16x4 xb = {s, s, s, s};
                f16x4 h = relu_h(xb * w1h + b1h);       // v_pk_fma_f16 + v_pk_max_f16
                f32x4 d = __builtin_amdgcn_mfma_f32_16x16x16f16(h, bfrag, cinit, 0, 0, 0);
                acc[t] += relu_f(d) * w3k4;
            }
        }
    }

    // ---- channel reduce (lane bits 0..3); r==0 lanes atomic the subnet sums ----
    #pragma unroll
    for (int t = 0; t < 4; ++t)
        #pragma unroll
        for (int j = 0; j < 4; ++j) {
            float v = acc[t][j];
            v += __shfl_xor(v, 1, 64);
            v += __shfl_xor(v, 2, 64);
            v += __shfl_xor(v, 4, 64);
            v += __shfl_xor(v, 8, 64);
            if (r == 0)
                atomicAdd(out + rowbase + w * 64 + t * 16 + g4 + j, v);
        }

    // ---- linear term + constants: g==0 lanes own rows t*16+r (no epilogue LDS re-read) --
    float b3s = 0.f;
    #pragma unroll
    for (int c = 0; c < FCHUNK; ++c) b3s += b3[f0 + c];   // uniform -> s_loads
    const float gconst = b3s + (fg == 0 ? bb[0] : 0.f);
    if (g == 0) {
        #pragma unroll
        for (int t = 0; t < 4; ++t)
            atomicAdd(out + rowbase + w * 64 + t * 16 + r, lin[t] + gconst);
    }
}

extern "C" void kernel_launch(void* const* d_in, const int* in_sizes, int n_in,
                              void* d_out, int out_size, void* d_ws, size_t ws_size,
                              hipStream_t stream) {
    const float* x  = (const float*)d_in[0];
    const float* la = (const float*)d_in[1];
    const float* bb = (const float*)d_in[2];
    const float* W1 = (const float*)d_in[3];
    const float* b1 = (const float*)d_in[4];
    const float* W2 = (const float*)d_in[5];
    const float* b2 = (const float*)d_in[6];
    const float* W3 = (const float*)d_in[7];
    const float* b3 = (const float*)d_in[8];
    float* out = (float*)d_out;

    (void)hipMemsetAsync(out, 0, (size_t)out_size * sizeof(float), stream);

    dim3 grid(2048), block(256);   // 128 row-blocks x 16 feature-groups
    hipLaunchKernelGGL(igann_kernel, grid, block, 0, stream,
                       x, la, bb, W1, b1, W2, b2, W3, b3, out);
}

// Round 21
// 110.614 us; speedup vs baseline: 1.3396x; 1.3396x over previous
//
#include <hip/hip_runtime.h>

// IGANN: per-feature 2-layer MLPs (1->16->16->1), summed over 256 features + linear term.
// R21 = R19 (rolled fi-loop, best 107.8) + two fixes isolated from R20's counter haul:
//     (1) W2R 16->20: R20 exposed SQ_LDS_BANK_CONFLICT=1.8M — the bfrag ds_read at 32-B
//         stride hits banks r*8 mod 32 = 4-way conflict (cost 1.58x, hottest LDS op).
//         Stride 20 f16 = 40 B -> banks r*10 mod 32 all-distinct -> conflict-free.
//         (R14's "dense=conflict-free" claim was WRONG; R9/R11's pad was right.)
//     (2) lin computed in-loop from staged xv f16 (R20 part b — innocuous; the regression
//         was the full unroll: VGPR 168, occupancy 10.6%). Epilogue LDS re-read deleted;
//         g==0 lanes deliver lin + b3s + bb.
//     Rolled fi-loop retained (R20 proved full unroll -> VGPR 168 collapse).
//     LDS 23552 B (>=6 blocks/CU; residency proven flat 4-8). Plain launch_bounds(256).

typedef float    f32x4 __attribute__((ext_vector_type(4)));
typedef _Float16 f16x4 __attribute__((ext_vector_type(4)));
typedef __fp16   pk16x2 __attribute__((ext_vector_type(2)));

__device__ __forceinline__ f16x4 cvt4(f32x4 v) {
    pk16x2 lo = __builtin_amdgcn_cvt_pkrtz(v[0], v[1]);
    pk16x2 hi = __builtin_amdgcn_cvt_pkrtz(v[2], v[3]);
    union { unsigned u[2]; f16x4 h; } un;
    un.u[0] = __builtin_bit_cast(unsigned, lo);
    un.u[1] = __builtin_bit_cast(unsigned, hi);
    return un.h;
}

__device__ __forceinline__ f16x4 relu_h(f16x4 v) {
    f16x4 z = {};
    return __builtin_elementwise_max(v, z);
}

__device__ __forceinline__ f32x4 relu_f(f32x4 v) {
    f32x4 z = {0.f, 0.f, 0.f, 0.f};
    return __builtin_elementwise_max(v, z);
}

#define FCHUNK 16   // features per block (16 groups of 16 = 256)
#define XR     20   // x LDS row stride in f16 (banks row*10 mod 32 distinct — conflict-free)
#define W2R    20   // W2 LDS row stride in f16 (banks r*10 mod 32 distinct — conflict-free)

__global__ __launch_bounds__(256) void igann_kernel(
    const float* __restrict__ x,  const float* __restrict__ la,
    const float* __restrict__ bb, const float* __restrict__ W1,
    const float* __restrict__ b1, const float* __restrict__ W2,
    const float* __restrict__ b2, const float* __restrict__ W3,
    const float* __restrict__ b3, float* __restrict__ out)
{
    const int tid = threadIdx.x;
    const int l   = tid & 63;     // lane
    const int w   = tid >> 6;     // wave in block (0..3)
    const int r   = l & 15;       // MFMA row m (A) / col n (D)
    const int g   = l >> 4;       // k-group
    const int g4  = g * 4;

    const int rb = blockIdx.x >> 4;    // row block (0..127), 256 rows each
    const int fg = blockIdx.x & 15;    // feature group (0..15)
    const int f0 = fg * FCHUNK;
    const int rowbase = rb * 256;

    __shared__ _Float16 xs [256 * XR];            // 10240 B: x slice [row][col16+pad]
    __shared__ _Float16 w2s[FCHUNK * 16 * W2R];   // 10240 B: [f][n][k16+pad]
    __shared__ _Float16 wbs[FCHUNK * 4 * 8];      //  1024 B: [f][g][w1 x4 | b1 x4]
    __shared__ float2   bws[FCHUNK * 16];         //  2048 B: [f][n] -> (b2, w3)
                                                  //  -> 23552 B total

    // ---- stage x slice (coalesced: 4 lanes cover one 64-B row-slice) ----
    {
        const int rr = tid >> 2;          // 0..63
        const int c4 = (tid & 3) * 4;     // 0,4,8,12
        #pragma unroll
        for (int it = 0; it < 4; ++it) {
            const int row = it * 64 + rr;
            f32x4 v = *(const f32x4*)(x + (size_t)(rowbase + row) * 256 + f0 + c4);
            *(f16x4*)(xs + row * XR + c4) = cvt4(v);
        }
    }
    // ---- stage W2 (thread tid owns (f,n)=(tid>>4, tid&15)) ----
    {
        const int f = tid >> 4, n = tid & 15;
        const float* src = W2 + ((size_t)(f0 + f) * 16 + n) * 16;
        _Float16* dst = w2s + (f * 16 + n) * W2R;
        #pragma unroll
        for (int q = 0; q < 4; ++q) {
            f32x4 v = *(const f32x4*)(src + q * 4);
            *(f16x4*)(dst + q * 4) = cvt4(v);
        }
    }
    // ---- stage interleaved W1|b1 (scalar f16 stores; thread tid owns (f,k)) ----
    {
        const int f = tid >> 4, k = tid & 15;
        const int base = f * 32 + (k >> 2) * 8 + (k & 3);   // [f][g][lo4|hi4]
        wbs[base]     = (_Float16)W1[(size_t)(f0 + f) * 16 + k];
        wbs[base + 4] = (_Float16)b1[(size_t)(f0 + f) * 16 + k];
    }
    // ---- stage (b2, w3) float2 pairs ----
    {
        const int f = tid >> 4, n = tid & 15;
        bws[tid] = make_float2(b2[(size_t)(f0 + f) * 16 + n],
                               W3[(size_t)(f0 + f) * 16 + n]);
    }
    __syncthreads();

    const _Float16* xw = xs + (w * 64 + r) * XR;

    f32x4 acc[4];     // [tile][j]: D row g4+j (batch row within tile), col r (channel)
    float lin[4];     // linear term for row t*16+r (duplicated across g; g==0 delivers)
    #pragma unroll
    for (int t = 0; t < 4; ++t) { acc[t] = (f32x4){0.f, 0.f, 0.f, 0.f}; lin[t] = 0.f; }

    for (int fi = 0; fi < FCHUNK; fi += 4) {   // rolled: R20 proved unroll -> VGPR blowup
        f16x4 xv[4];
        #pragma unroll
        for (int t = 0; t < 4; ++t)
            xv[t] = *(const f16x4*)(xw + t * 16 * XR + fi);

        // linear term from the staged f16 values (la wave-uniform -> s_loads)
        #pragma unroll
        for (int t = 0; t < 4; ++t)
            #pragma unroll
            for (int c = 0; c < 4; ++c)
                lin[t] = fmaf((float)xv[t][c], la[f0 + fi + c], lin[t]);

        #pragma unroll
        for (int u = 0; u < 4; ++u) {
            const int f = fi + u;
            // adjacent f16x4 reads (8 B apart) -> ds_read2_b64
            f16x4 w1h   = *(const f16x4*)(wbs + f * 32 + g * 8);
            f16x4 b1h   = *(const f16x4*)(wbs + f * 32 + g * 8 + 4);
            f16x4 bfrag = *(const f16x4*)(w2s + (f * 16 + r) * W2R + g4);
            const float2 bw = bws[f * 16 + r];          // one ds_read_b64
            const f32x4 cinit = {bw.x, bw.x, bw.x, bw.x};   // b2 folded into MFMA C
            const f32x4 w3k4  = {bw.y, bw.y, bw.y, bw.y};

            #pragma unroll
            for (int t = 0; t < 4; ++t) {
                const _Float16 s = xv[t][u];
                f16x4 xb = {s, s, s, s};
                f16x4 h = relu_h(xb * w1h + b1h);       // v_pk_fma_f16 + v_pk_max_f16
                f32x4 d = __builtin_amdgcn_mfma_f32_16x16x16f16(h, bfrag, cinit, 0, 0, 0);
                acc[t] += relu_f(d) * w3k4;
            }
        }
    }

    // ---- channel reduce (lane bits 0..3); r==0 lanes atomic the subnet sums ----
    #pragma unroll
    for (int t = 0; t < 4; ++t)
        #pragma unroll
        for (int j = 0; j < 4; ++j) {
            float v = acc[t][j];
            v += __shfl_xor(v, 1, 64);
            v += __shfl_xor(v, 2, 64);
            v += __shfl_xor(v, 4, 64);
            v += __shfl_xor(v, 8, 64);
            if (r == 0)
                atomicAdd(out + rowbase + w * 64 + t * 16 + g4 + j, v);
        }

    // ---- linear term + constants: g==0 lanes own rows t*16+r (no epilogue LDS re-read) --
    float b3s = 0.f;
    #pragma unroll
    for (int c = 0; c < FCHUNK; ++c) b3s += b3[f0 + c];   // uniform -> s_loads
    const float gconst = b3s + (fg == 0 ? bb[0] : 0.f);
    if (g == 0) {
        #pragma unroll
        for (int t = 0; t < 4; ++t)
            atomicAdd(out + rowbase + w * 64 + t * 16 + r, lin[t] + gconst);
    }
}

extern "C" void kernel_launch(void* const* d_in, const int* in_sizes, int n_in,
                              void* d_out, int out_size, void* d_ws, size_t ws_size,
                              hipStream_t stream) {
    const float* x  = (const float*)d_in[0];
    const float* la = (const float*)d_in[1];
    const float* bb = (const float*)d_in[2];
    const float* W1 = (const float*)d_in[3];
    const float* b1 = (const float*)d_in[4];
    const float* W2 = (const float*)d_in[5];
    const float* b2 = (const float*)d_in[6];
    const float* W3 = (const float*)d_in[7];
    const float* b3 = (const float*)d_in[8];
    float* out = (float*)d_out;

    (void)hipMemsetAsync(out, 0, (size_t)out_size * sizeof(float), stream);

    dim3 grid(2048), block(256);   // 128 row-blocks x 16 feature-groups
    hipLaunchKernelGGL(igann_kernel, grid, block, 0, stream,
                       x, la, bb, W1, b1, W2, b2, W3, b3, out);
}

// Round 22
// 107.216 us; speedup vs baseline: 1.3821x; 1.0317x over previous
//
#include <hip/hip_runtime.h>

// IGANN: per-feature 2-layer MLPs (1->16->16->1), summed over 256 features + linear term.
// R22 = R19 VERBATIM (best: 107.8) + exactly one change: W2R 16 -> 20.
//     Isolates the bank-conflict fix R21 confounded with a bad lin-in-loop change
//     (R21's in-loop lin quadrupled the lin VALU work via g-duplication -> +12K VALU/block,
//     net regression; reverted to R19's per-thread epilogue here).
//     W2R=20: bfrag ds_read banks r*10 mod 32 all-distinct -> kills the 1.8M conflict
//     cycles R20 exposed (4-way on the 32-B-stride bfrag read, cost 1.58x per m136).
//     Everything else R19: rolled fi-loop (R20: full unroll -> VGPR 168, 10% occ),
//     interleaved W1|b1 ds_read2_b64, (b2,w3) float2, plain launch_bounds(256),
//     grid 2048 = 128 row-blocks x 16 feature-groups.

typedef float    f32x4 __attribute__((ext_vector_type(4)));
typedef _Float16 f16x4 __attribute__((ext_vector_type(4)));
typedef __fp16   pk16x2 __attribute__((ext_vector_type(2)));

__device__ __forceinline__ f16x4 cvt4(f32x4 v) {
    pk16x2 lo = __builtin_amdgcn_cvt_pkrtz(v[0], v[1]);
    pk16x2 hi = __builtin_amdgcn_cvt_pkrtz(v[2], v[3]);
    union { unsigned u[2]; f16x4 h; } un;
    un.u[0] = __builtin_bit_cast(unsigned, lo);
    un.u[1] = __builtin_bit_cast(unsigned, hi);
    return un.h;
}

__device__ __forceinline__ f16x4 relu_h(f16x4 v) {
    f16x4 z = {};
    return __builtin_elementwise_max(v, z);
}

__device__ __forceinline__ f32x4 relu_f(f32x4 v) {
    f32x4 z = {0.f, 0.f, 0.f, 0.f};
    return __builtin_elementwise_max(v, z);
}

#define FCHUNK 16   // features per block (16 groups of 16 = 256)
#define XR     20   // x LDS row stride in f16 (banks row*10 mod 32 distinct — conflict-free)
#define W2R    20   // W2 LDS row stride in f16 (banks r*10 mod 32 distinct — conflict-free)

__global__ __launch_bounds__(256) void igann_kernel(
    const float* __restrict__ x,  const float* __restrict__ la,
    const float* __restrict__ bb, const float* __restrict__ W1,
    const float* __restrict__ b1, const float* __restrict__ W2,
    const float* __restrict__ b2, const float* __restrict__ W3,
    const float* __restrict__ b3, float* __restrict__ out)
{
    const int tid = threadIdx.x;
    const int l   = tid & 63;     // lane
    const int w   = tid >> 6;     // wave in block (0..3)
    const int r   = l & 15;       // MFMA row m (A) / col n (D)
    const int g   = l >> 4;       // k-group
    const int g4  = g * 4;

    const int rb = blockIdx.x >> 4;    // row block (0..127), 256 rows each
    const int fg = blockIdx.x & 15;    // feature group (0..15)
    const int f0 = fg * FCHUNK;
    const int rowbase = rb * 256;

    __shared__ _Float16 xs [256 * XR];            // 10240 B: x slice [row][col16+pad]
    __shared__ _Float16 w2s[FCHUNK * 16 * W2R];   // 10240 B: [f][n][k16+pad]
    __shared__ _Float16 wbs[FCHUNK * 4 * 8];      //  1024 B: [f][g][w1 x4 | b1 x4]
    __shared__ float2   bws[FCHUNK * 16];         //  2048 B: [f][n] -> (b2, w3)
                                                  //  -> 23552 B total

    // ---- stage x slice (coalesced: 4 lanes cover one 64-B row-slice) ----
    {
        const int rr = tid >> 2;          // 0..63
        const int c4 = (tid & 3) * 4;     // 0,4,8,12
        #pragma unroll
        for (int it = 0; it < 4; ++it) {
            const int row = it * 64 + rr;
            f32x4 v = *(const f32x4*)(x + (size_t)(rowbase + row) * 256 + f0 + c4);
            *(f16x4*)(xs + row * XR + c4) = cvt4(v);
        }
    }
    // ---- stage W2 (thread tid owns (f,n)=(tid>>4, tid&15)) ----
    {
        const int f = tid >> 4, n = tid & 15;
        const float* src = W2 + ((size_t)(f0 + f) * 16 + n) * 16;
        _Float16* dst = w2s + (f * 16 + n) * W2R;
        #pragma unroll
        for (int q = 0; q < 4; ++q) {
            f32x4 v = *(const f32x4*)(src + q * 4);
            *(f16x4*)(dst + q * 4) = cvt4(v);
        }
    }
    // ---- stage interleaved W1|b1 (scalar f16 stores; thread tid owns (f,k)) ----
    {
        const int f = tid >> 4, k = tid & 15;
        const int base = f * 32 + (k >> 2) * 8 + (k & 3);   // [f][g][lo4|hi4]
        wbs[base]     = (_Float16)W1[(size_t)(f0 + f) * 16 + k];
        wbs[base + 4] = (_Float16)b1[(size_t)(f0 + f) * 16 + k];
    }
    // ---- stage (b2, w3) float2 pairs ----
    {
        const int f = tid >> 4, n = tid & 15;
        bws[tid] = make_float2(b2[(size_t)(f0 + f) * 16 + n],
                               W3[(size_t)(f0 + f) * 16 + n]);
    }
    __syncthreads();

    const _Float16* xw = xs + (w * 64 + r) * XR;

    f32x4 acc[4];     // [tile][j]: D row g4+j (batch row within tile), col r (channel)
    #pragma unroll
    for (int t = 0; t < 4; ++t) acc[t] = (f32x4){0.f, 0.f, 0.f, 0.f};

    for (int fi = 0; fi < FCHUNK; fi += 4) {   // rolled: keeps register pressure down
        f16x4 xv[4];
        #pragma unroll
        for (int t = 0; t < 4; ++t)
            xv[t] = *(const f16x4*)(xw + t * 16 * XR + fi);

        #pragma unroll
        for (int u = 0; u < 4; ++u) {
            const int f = fi + u;
            // adjacent f16x4 reads (8 B apart) -> ds_read2_b64
            f16x4 w1h   = *(const f16x4*)(wbs + f * 32 + g * 8);
            f16x4 b1h   = *(const f16x4*)(wbs + f * 32 + g * 8 + 4);
            f16x4 bfrag = *(const f16x4*)(w2s + (f * 16 + r) * W2R + g4);
            const float2 bw = bws[f * 16 + r];          // one ds_read_b64
            const f32x4 cinit = {bw.x, bw.x, bw.x, bw.x};   // b2 folded into MFMA C
            const f32x4 w3k4  = {bw.y, bw.y, bw.y, bw.y};

            #pragma unroll
            for (int t = 0; t < 4; ++t) {
                const _Float16 s = xv[t][u];
                f16x4 xb = {s, s, s, s};
                f16x4 h = relu_h(xb * w1h + b1h);       // v_pk_fma_f16 + v_pk_max_f16
                f32x4 d = __builtin_amdgcn_mfma_f32_16x16x16f16(h, bfrag, cinit, 0, 0, 0);
                acc[t] += relu_f(d) * w3k4;
            }
        }
    }

    // ---- channel reduce (lane bits 0..3); r==0 lanes atomic the subnet sums ----
    #pragma unroll
    for (int t = 0; t < 4; ++t)
        #pragma unroll
        for (int j = 0; j < 4; ++j) {
            float v = acc[t][j];
            v += __shfl_xor(v, 1, 64);
            v += __shfl_xor(v, 2, 64);
            v += __shfl_xor(v, 4, 64);
            v += __shfl_xor(v, 8, 64);
            if (r == 0)
                atomicAdd(out + rowbase + w * 64 + t * 16 + g4 + j, v);
        }

    // ---- linear term + constants: thread tid owns local row tid (xs intact) ----
    float b3s = 0.f;
    #pragma unroll
    for (int c = 0; c < FCHUNK; ++c) b3s += b3[f0 + c];   // uniform -> s_loads
    float lin = 0.f;
    const _Float16* xrow = xs + tid * XR;
    #pragma unroll
    for (int c = 0; c < FCHUNK; ++c)
        lin = fmaf((float)xrow[c], la[f0 + c], lin);       // la uniform -> s_loads
    atomicAdd(out + rowbase + tid, lin + b3s + (fg == 0 ? bb[0] : 0.f));
}

extern "C" void kernel_launch(void* const* d_in, const int* in_sizes, int n_in,
                              void* d_out, int out_size, void* d_ws, size_t ws_size,
                              hipStream_t stream) {
    const float* x  = (const float*)d_in[0];
    const float* la = (const float*)d_in[1];
    const float* bb = (const float*)d_in[2];
    const float* W1 = (const float*)d_in[3];
    const float* b1 = (const float*)d_in[4];
    const float* W2 = (const float*)d_in[5];
    const float* b2 = (const float*)d_in[6];
    const float* W3 = (const float*)d_in[7];
    const float* b3 = (const float*)d_in[8];
    float* out = (float*)d_out;

    (void)hipMemsetAsync(out, 0, (size_t)out_size * sizeof(float), stream);

    dim3 grid(2048), block(256);   // 128 row-blocks x 16 feature-groups
    hipLaunchKernelGGL(igann_kernel, grid, block, 0, stream,
                       x, la, bb, W1, b1, W2, b2, W3, b3, out);
}